// Round 11
// baseline (477.533 us; speedup 1.0000x reference)
//
#include <hip/hip_runtime.h>

// GCN 3-layer: N=50000, E=1.6M, D_IN=256, H=128, D_OUT=64, fp32 in/out.
// CSR build via LDS histogram (no global atomics): 64 blocks x 4 bin-slices,
// LDS atomicAdd returns within-(block,bin) slot; colscan makes per-block
// exclusive offsets; fill is an atomic-free scatter.
// Per layer: split-bf16 MFMA GEMM -> CSR-SpMM over bf16 rows (pre-scaled dinv).

constexpr int DIN = 256;
constexpr int HID = 128;
constexpr int DOUT = 64;
constexpr int NBLK = 64;      // histogram blocks
constexpr int SLICE = 12544;  // bins per slice (49KB LDS)

typedef unsigned short ushort_t;
typedef unsigned int uint_t;
typedef __attribute__((ext_vector_type(8))) short bf16x8;
typedef __attribute__((ext_vector_type(4))) float f32x4;

__device__ inline ushort_t f2bf(float f) {
  uint_t u = __float_as_uint(f);
  u += 0x7FFF + ((u >> 16) & 1);  // RNE
  return (ushort_t)(u >> 16);
}
__device__ inline float bf2f(ushort_t b) {
  return __uint_as_float(((uint_t)b) << 16);
}

// ---------- weight prep: W[K][F] fp32 -> fragment bf16 hi/lo ----------
// Layout: Bp[t = n/16][s = k/32][lane = (k/8 % 4)*16 + n%16][j = k%8]

__device__ inline void wprep_one(const float* __restrict__ W, ushort_t* __restrict__ Bhi,
                                 ushort_t* __restrict__ Blo, int K, int F, int i) {
  int k = i / F, nn = i % F;
  int t = nn >> 4, s = k >> 5, q = (k >> 3) & 3, j = k & 7;
  int lane = q * 16 + (nn & 15);
  int KS = K >> 5;
  size_t idx = (((size_t)t * KS + s) * 64 + (size_t)lane) * 8 + j;
  float w = W[i];
  ushort_t h = f2bf(w);
  float r = w - bf2f(h);
  Bhi[idx] = h;
  Blo[idx] = f2bf(r);
}

__global__ __launch_bounds__(256) void wprep_kernel(
    const float* __restrict__ W1, ushort_t* __restrict__ W1hi, ushort_t* __restrict__ W1lo,
    const float* __restrict__ W2, ushort_t* __restrict__ W2hi, ushort_t* __restrict__ W2lo,
    const float* __restrict__ W3, ushort_t* __restrict__ W3hi, ushort_t* __restrict__ W3lo) {
  int idx = blockIdx.x * 256 + threadIdx.x;
  constexpr int S1 = DIN * HID;        // 32768
  constexpr int S2 = S1 + HID * HID;   // 49152
  constexpr int S3 = S2 + HID * DOUT;  // 57344
  if (idx < S1) wprep_one(W1, W1hi, W1lo, DIN, HID, idx);
  else if (idx < S2) wprep_one(W2, W2hi, W2lo, HID, HID, idx - S1);
  else if (idx < S3) wprep_one(W3, W3hi, W3lo, HID, DOUT, idx - S2);
}

// ---------- split-bf16 MFMA GEMM (device fn) ----------
// 256 threads = 4 waves; 64 rows per block-id; wave w: rows +16w..+16w+15.
// acc = Ahi*Bhi + Alo*Bhi + Ahi*Blo (fp32 accum; lo*lo dropped, ~2^-18 rel).

template <int K, int F, bool SCALE>
__device__ inline void gemm_mfma_dev(const float* __restrict__ X,
    const ushort_t* __restrict__ Bhi, const ushort_t* __restrict__ Blo,
    const float* __restrict__ dinv, ushort_t* __restrict__ T, int n, int bid) {
  constexpr int NT = F / 16;   // n-tiles
  constexpr int KS = K / 32;   // k-steps
  int wave = threadIdx.x >> 6;
  int lane = threadIdx.x & 63;
  int q = lane >> 4;
  int m = lane & 15;
  int arow = bid * 64 + wave * 16 + m;
  bool valid = arow < n;
  const float* xrow = X + (size_t)arow * K;

  f32x4 acc[NT];
#pragma unroll
  for (int t = 0; t < NT; ++t) acc[t] = (f32x4){0.f, 0.f, 0.f, 0.f};

  for (int s = 0; s < KS; ++s) {
    float av[8];
    if (valid) {
      float4 u0 = *(const float4*)(xrow + s * 32 + q * 8);
      float4 u1 = *(const float4*)(xrow + s * 32 + q * 8 + 4);
      av[0] = u0.x; av[1] = u0.y; av[2] = u0.z; av[3] = u0.w;
      av[4] = u1.x; av[5] = u1.y; av[6] = u1.z; av[7] = u1.w;
    } else {
#pragma unroll
      for (int j = 0; j < 8; ++j) av[j] = 0.f;
    }
    bf16x8 ahi, alo;
#pragma unroll
    for (int j = 0; j < 8; ++j) {
      ushort_t h = f2bf(av[j]);
      ahi[j] = (short)h;
      alo[j] = (short)f2bf(av[j] - bf2f(h));
    }
#pragma unroll
    for (int t = 0; t < NT; ++t) {
      size_t boff = (((size_t)t * KS + s) * 64 + (size_t)lane) * 8;
      bf16x8 bh = *(const bf16x8*)(Bhi + boff);
      bf16x8 bl = *(const bf16x8*)(Blo + boff);
      acc[t] = __builtin_amdgcn_mfma_f32_16x16x32_bf16(ahi, bh, acc[t], 0, 0, 0);
      acc[t] = __builtin_amdgcn_mfma_f32_16x16x32_bf16(alo, bh, acc[t], 0, 0, 0);
      acc[t] = __builtin_amdgcn_mfma_f32_16x16x32_bf16(ahi, bl, acc[t], 0, 0, 0);
    }
  }

  int orow_base = bid * 64 + wave * 16 + q * 4;
#pragma unroll
  for (int r = 0; r < 4; ++r) {
    int orow = orow_base + r;
    if (orow >= n) continue;
    float sc = SCALE ? dinv[orow] : 1.0f;
    ushort_t* trow = T + (size_t)orow * F + m;
#pragma unroll
    for (int t = 0; t < NT; ++t) trow[t * 16] = f2bf(sc * acc[t][r]);
  }
}

template <int K, int F>
__global__ __launch_bounds__(256) void gemm_mfma_kernel(const float* __restrict__ X,
    const ushort_t* __restrict__ Bhi, const ushort_t* __restrict__ Blo,
    const float* __restrict__ dinv, ushort_t* __restrict__ T, int n) {
  gemm_mfma_dev<K, F, true>(X, Bhi, Blo, dinv, T, n, blockIdx.x);
}

// ---------- fused H: [LDS histogram (NBLK blocks) | gemm1 unscaled] ----------
// histo: per block, 4 slice passes over its edge chunk; LDS atomicAdd gives
// within-(block,bin) slot. No global atomics anywhere.

__global__ __launch_bounds__(256) void fusedH_kernel(
    const int* __restrict__ dst, int* __restrict__ blockhist,
    int* __restrict__ lslot, int e, int chunk, int n,
    const float* __restrict__ X, const ushort_t* __restrict__ Bhi,
    const ushort_t* __restrict__ Blo, ushort_t* __restrict__ T, int nn) {
  __shared__ int h[SLICE];
  if ((int)blockIdx.x < NBLK) {
    int b = blockIdx.x;
    int i0 = b * chunk;
    int i1 = i0 + chunk; if (i1 > e) i1 = e;
#pragma unroll 1
    for (int s = 0; s < 4; ++s) {
      int base = s * SLICE;
      for (int j = threadIdx.x; j < SLICE; j += 256) h[j] = 0;
      __syncthreads();
      for (int i = i0 + threadIdx.x; i < i1; i += 256) {
        int r = dst[i] - base;
        if (r >= 0 && r < SLICE) lslot[i] = atomicAdd(&h[r], 1);
      }
      __syncthreads();
      for (int j = threadIdx.x; j < SLICE; j += 256) {
        int bin = base + j;
        if (bin < n) blockhist[(size_t)b * n + bin] = h[j];
      }
      __syncthreads();
    }
  } else {
    gemm_mfma_dev<DIN, HID, false>(X, Bhi, Blo, nullptr, T, nn, (int)blockIdx.x - NBLK);
  }
}

// ---------- colscan: exclusive scan over blocks per bin; emit cnt ----------

__global__ __launch_bounds__(256) void colscan_kernel(int* __restrict__ blockhist,
    int* __restrict__ cnt, int n) {
  int d = blockIdx.x * 256 + threadIdx.x;
  if (d >= n) return;
  int run = 0;
#pragma unroll 4
  for (int b = 0; b < NBLK; ++b) {
    size_t idx = (size_t)b * n + d;
    int c = blockhist[idx];
    blockhist[idx] = run;
    run += c;
  }
  cnt[d] = run;  // edges into d (deg-1)
}

// ---------- 3-phase exclusive scan of cnt, 1024 elems / block ----------

__global__ __launch_bounds__(256) void scanA_kernel(const int* __restrict__ cnt,
    int* __restrict__ blocksum, int n) {
  __shared__ int sums[256];
  int t = threadIdx.x;
  int base = blockIdx.x * 1024 + t * 4;
  int local = 0;
#pragma unroll
  for (int k = 0; k < 4; ++k) {
    int i = base + k;
    if (i < n) local += cnt[i];
  }
  sums[t] = local;
  __syncthreads();
  for (int off = 128; off > 0; off >>= 1) {
    if (t < off) sums[t] += sums[t + off];
    __syncthreads();
  }
  if (t == 0) blocksum[blockIdx.x] = sums[0];
}

__global__ __launch_bounds__(64) void scanB_kernel(int* __restrict__ blocksum, int nb) {
  int lane = threadIdx.x;
  int carry = 0;
  for (int base = 0; base < nb; base += 64) {
    int i = base + lane;
    int orig = (i < nb) ? blocksum[i] : 0;
    int v = orig;
#pragma unroll
    for (int off = 1; off < 64; off <<= 1) {
      int u = __shfl_up(v, off, 64);
      if (lane >= off) v += u;
    }
    int total = __shfl(v, 63, 64);
    if (i < nb) blocksum[i] = carry + v - orig;  // exclusive
    carry += total;
  }
}

__global__ __launch_bounds__(256) void scanC_kernel(const int* __restrict__ cnt,
    const int* __restrict__ blocksum, int* __restrict__ row_start,
    float* __restrict__ dinv, int n) {
  __shared__ int sums[256];
  int t = threadIdx.x;
  int base = blockIdx.x * 1024 + t * 4;
  int c[4];
  int local = 0;
#pragma unroll
  for (int k = 0; k < 4; ++k) {
    int i = base + k;
    c[k] = (i < n) ? cnt[i] : 0;
    local += c[k];
  }
  sums[t] = local;
  __syncthreads();
  for (int off = 1; off < 256; off <<= 1) {
    int v = (t >= off) ? sums[t - off] : 0;
    __syncthreads();
    sums[t] += v;
    __syncthreads();
  }
  int run = blocksum[blockIdx.x] + sums[t] - local;  // exclusive offset
#pragma unroll
  for (int k = 0; k < 4; ++k) {
    int i = base + k;
    if (i < n) {
      row_start[i] = run;
      dinv[i] = rsqrtf((float)(c[k] + 1));
      run += c[k];
    }
  }
}

// ---------- fused B: [fill | scaleT] ----------

__global__ __launch_bounds__(256) void fusedB_kernel(
    const int* __restrict__ src, const int* __restrict__ dst,
    const int* __restrict__ lslot, const int* __restrict__ blockhist,
    const int* __restrict__ row_start, int* __restrict__ col,
    int e, int chunk, int fblocks,
    ushort_t* __restrict__ T, const float* __restrict__ dinv, int n) {
  if ((int)blockIdx.x < fblocks) {
    int i = blockIdx.x * 256 + threadIdx.x;
    if (i >= e) return;
    int d = dst[i];
    int b = i / chunk;
    int pos = row_start[d] + blockhist[(size_t)b * n + d] + lslot[i];
    col[pos] = src[i];
  } else {
    int idx = ((int)blockIdx.x - fblocks) * 256 + threadIdx.x;  // 8 bf16 each
    int total = n * (HID / 8);
    if (idx >= total) return;
    int row = idx >> 4;  // 16 chunks of 8 per row (HID=128)
    float sc = dinv[row];
    uint4* p = (uint4*)T + idx;
    uint4 v = *p;
    uint_t w[4] = {v.x, v.y, v.z, v.w};
#pragma unroll
    for (int j = 0; j < 4; ++j) {
      float lo = sc * bf2f((ushort_t)(w[j] & 0xFFFF));
      float hi = sc * bf2f((ushort_t)(w[j] >> 16));
      w[j] = (uint_t)f2bf(lo) | ((uint_t)f2bf(hi) << 16);
    }
    v.x = w[0]; v.y = w[1]; v.z = w[2]; v.w = w[3];
    *p = v;
  }
}

// ---------- CSR SpMM: out[d] = dinv[d]*(t'[d] + sum_c t'[c]) + b, opt ReLU ----------
// t' rows bf16, pre-scaled by dinv[row]. TWO destination nodes per wave.
// Row descriptors forced scalar via readfirstlane -> col reads become s_loads.

template <int F, bool RELU>
__global__ __launch_bounds__(256) void spmm_kernel(const ushort_t* __restrict__ t,
    const int* __restrict__ row_start, const int* __restrict__ cntArr,
    const int* __restrict__ col, const float* __restrict__ dinv,
    const float* __restrict__ bias, float* __restrict__ out, int n) {
  int gw = (int)((blockIdx.x * 256u + threadIdx.x) >> 6);
  int lane = threadIdx.x & 63;
  int n0 = gw * 2;
  int n1 = n0 + 1;
  if (n0 >= n) return;
  bool h1 = (n1 < n);
  int rs0 = __builtin_amdgcn_readfirstlane(row_start[n0]);
  int e0 = __builtin_amdgcn_readfirstlane(cntArr[n0]);
  int rs1 = h1 ? __builtin_amdgcn_readfirstlane(row_start[n1]) : 0;
  int e1 = h1 ? __builtin_amdgcn_readfirstlane(cntArr[n1]) : 0;
  float di0 = dinv[n0];
  float di1 = h1 ? dinv[n1] : 0.f;

  if constexpr (F == 128) {
    uint_t s0 = ((const uint_t*)(t + (size_t)n0 * F))[lane];
    float ax0 = bf2f((ushort_t)(s0 & 0xFFFF)), ay0 = bf2f((ushort_t)(s0 >> 16));
    float ax1 = 0.f, ay1 = 0.f;
    if (h1) {
      uint_t s1 = ((const uint_t*)(t + (size_t)n1 * F))[lane];
      ax1 = bf2f((ushort_t)(s1 & 0xFFFF)); ay1 = bf2f((ushort_t)(s1 >> 16));
    }
    int p0 = rs0, q0 = rs0 + e0;
    int p1 = rs1, q1 = rs1 + e1;
    while (p0 + 4 <= q0 && p1 + 4 <= q1) {
      int c[8];
      uint_t v[8];
#pragma unroll
      for (int j = 0; j < 4; ++j) { c[j] = col[p0 + j]; c[4 + j] = col[p1 + j]; }
#pragma unroll
      for (int j = 0; j < 8; ++j) v[j] = ((const uint_t*)(t + (size_t)c[j] * F))[lane];
#pragma unroll
      for (int j = 0; j < 4; ++j) {
        ax0 += bf2f((ushort_t)(v[j] & 0xFFFF));
        ay0 += bf2f((ushort_t)(v[j] >> 16));
        ax1 += bf2f((ushort_t)(v[4 + j] & 0xFFFF));
        ay1 += bf2f((ushort_t)(v[4 + j] >> 16));
      }
      p0 += 4; p1 += 4;
    }
    for (; p0 + 4 <= q0; p0 += 4) {
      int c[4]; uint_t v[4];
#pragma unroll
      for (int j = 0; j < 4; ++j) c[j] = col[p0 + j];
#pragma unroll
      for (int j = 0; j < 4; ++j) v[j] = ((const uint_t*)(t + (size_t)c[j] * F))[lane];
#pragma unroll
      for (int j = 0; j < 4; ++j) {
        ax0 += bf2f((ushort_t)(v[j] & 0xFFFF)); ay0 += bf2f((ushort_t)(v[j] >> 16));
      }
    }
    for (; p0 < q0; ++p0) {
      uint_t v = ((const uint_t*)(t + (size_t)col[p0] * F))[lane];
      ax0 += bf2f((ushort_t)(v & 0xFFFF)); ay0 += bf2f((ushort_t)(v >> 16));
    }
    for (; p1 + 4 <= q1; p1 += 4) {
      int c[4]; uint_t v[4];
#pragma unroll
      for (int j = 0; j < 4; ++j) c[j] = col[p1 + j];
#pragma unroll
      for (int j = 0; j < 4; ++j) v[j] = ((const uint_t*)(t + (size_t)c[j] * F))[lane];
#pragma unroll
      for (int j = 0; j < 4; ++j) {
        ax1 += bf2f((ushort_t)(v[j] & 0xFFFF)); ay1 += bf2f((ushort_t)(v[j] >> 16));
      }
    }
    for (; p1 < q1; ++p1) {
      uint_t v = ((const uint_t*)(t + (size_t)col[p1] * F))[lane];
      ax1 += bf2f((ushort_t)(v & 0xFFFF)); ay1 += bf2f((ushort_t)(v >> 16));
    }
    float bx = bias[2 * lane], by = bias[2 * lane + 1];
    ax0 = fmaf(di0, ax0, bx); ay0 = fmaf(di0, ay0, by);
    if constexpr (RELU) { ax0 = fmaxf(ax0, 0.f); ay0 = fmaxf(ay0, 0.f); }
    float2 o0; o0.x = ax0; o0.y = ay0;
    ((float2*)(out + (size_t)n0 * F))[lane] = o0;
    if (h1) {
      ax1 = fmaf(di1, ax1, bx); ay1 = fmaf(di1, ay1, by);
      if constexpr (RELU) { ax1 = fmaxf(ax1, 0.f); ay1 = fmaxf(ay1, 0.f); }
      float2 o1; o1.x = ax1; o1.y = ay1;
      ((float2*)(out + (size_t)n1 * F))[lane] = o1;
    }
  } else {  // F == 64: one bf16 per lane
    float a0 = bf2f(t[(size_t)n0 * F + lane]);
    float a1 = h1 ? bf2f(t[(size_t)n1 * F + lane]) : 0.f;
    int p0 = rs0, q0 = rs0 + e0;
    int p1 = rs1, q1 = rs1 + e1;
    while (p0 + 4 <= q0 && p1 + 4 <= q1) {
      int c[8];
      ushort_t v[8];
#pragma unroll
      for (int j = 0; j < 4; ++j) { c[j] = col[p0 + j]; c[4 + j] = col[p1 + j]; }
#pragma unroll
      for (int j = 0; j < 8; ++j) v[j] = t[(size_t)c[j] * F + lane];
#pragma unroll
      for (int j = 0; j < 4; ++j) { a0 += bf2f(v[j]); a1 += bf2f(v[4 + j]); }
      p0 += 4; p1 += 4;
    }
    for (; p0 + 4 <= q0; p0 += 4) {
      int c[4]; ushort_t v[4];
#pragma unroll
      for (int j = 0; j < 4; ++j) c[j] = col[p0 + j];
#pragma unroll
      for (int j = 0; j < 4; ++j) v[j] = t[(size_t)c[j] * F + lane];
#pragma unroll
      for (int j = 0; j < 4; ++j) a0 += bf2f(v[j]);
    }
    for (; p0 < q0; ++p0) a0 += bf2f(t[(size_t)col[p0] * F + lane]);
    for (; p1 + 4 <= q1; p1 += 4) {
      int c[4]; ushort_t v[4];
#pragma unroll
      for (int j = 0; j < 4; ++j) c[j] = col[p1 + j];
#pragma unroll
      for (int j = 0; j < 4; ++j) v[j] = t[(size_t)c[j] * F + lane];
#pragma unroll
      for (int j = 0; j < 4; ++j) a1 += bf2f(v[j]);
    }
    for (; p1 < q1; ++p1) a1 += bf2f(t[(size_t)col[p1] * F + lane]);
    float b = bias[lane];
    a0 = fmaf(di0, a0, b);
    if constexpr (RELU) a0 = fmaxf(a0, 0.f);
    out[(size_t)n0 * F + lane] = a0;
    if (h1) {
      a1 = fmaf(di1, a1, b);
      if constexpr (RELU) a1 = fmaxf(a1, 0.f);
      out[(size_t)n1 * F + lane] = a1;
    }
  }
}

// ---------- launch ----------

extern "C" void kernel_launch(void* const* d_in, const int* in_sizes, int n_in,
                              void* d_out, int out_size, void* d_ws, size_t ws_size,
                              hipStream_t stream) {
  const float* x  = (const float*)d_in[0];
  const float* W1 = (const float*)d_in[1];
  const float* b1 = (const float*)d_in[2];
  const float* W2 = (const float*)d_in[3];
  const float* b2 = (const float*)d_in[4];
  const float* W3 = (const float*)d_in[5];
  const float* b3 = (const float*)d_in[6];
  const int* ei   = (const int*)d_in[7];  // harness delivers integers as int32

  int n = in_sizes[0] / DIN;
  int e = in_sizes[7] / 2;
  const int* src = ei;
  const int* dst = ei + e;
  int chunk = (e + NBLK - 1) / NBLK;

  char* ws = (char*)d_ws;
  size_t off = 0;
  auto alloc = [&](size_t bytes) -> void* {
    off = (off + 255) & ~(size_t)255;
    void* p = ws + off;
    off += bytes;
    return p;
  };
  int nscan = (n + 1023) / 1024;
  int*      blockhist = (int*)alloc((size_t)NBLK * n * 4);     // 12.8 MB
  int*      lslot     = (int*)alloc((size_t)e * 4);
  int*      cnt       = (int*)alloc((size_t)n * 4);
  float*    dinv      = (float*)alloc((size_t)n * 4);
  int*      row_start = (int*)alloc((size_t)n * 4);
  int*      blocksum  = (int*)alloc((size_t)nscan * 4);
  int*      col       = (int*)alloc((size_t)e * 4);
  ushort_t* T         = (ushort_t*)alloc((size_t)n * HID * 2);  // bf16 GEMM out
  float*    Hf        = (float*)alloc((size_t)n * HID * 4);     // fp32 SpMM out
  ushort_t* W1hi      = (ushort_t*)alloc((size_t)DIN * HID * 2);
  ushort_t* W1lo      = (ushort_t*)alloc((size_t)DIN * HID * 2);
  ushort_t* W2hi      = (ushort_t*)alloc((size_t)HID * HID * 2);
  ushort_t* W2lo      = (ushort_t*)alloc((size_t)HID * HID * 2);
  ushort_t* W3hi      = (ushort_t*)alloc((size_t)HID * DOUT * 2);
  ushort_t* W3lo      = (ushort_t*)alloc((size_t)HID * DOUT * 2);
  (void)ws_size;

  int eb256 = (e + 255) / 256;
  int gemm_blocks = (n + 63) / 64;
  int nwaves = (n + 1) / 2;                 // 2 nodes per wave
  int spmm_blocks = (nwaves + 3) / 4;       // 4 waves per block
  constexpr int WPREP_TOTAL = DIN * HID + HID * HID + HID * DOUT;  // 57344
  int wblocks = (WPREP_TOTAL + 255) / 256;  // 224
  int sblocks = (n * (HID / 8) + 255) / 256;  // scaleT blocks

  wprep_kernel<<<wblocks, 256, 0, stream>>>(
      W1, W1hi, W1lo, W2, W2hi, W2lo, W3, W3hi, W3lo);
  fusedH_kernel<<<NBLK + gemm_blocks, 256, 0, stream>>>(
      dst, blockhist, lslot, e, chunk, n,
      x, W1hi, W1lo, T, n);
  colscan_kernel<<<(n + 255) / 256, 256, 0, stream>>>(blockhist, cnt, n);
  scanA_kernel<<<nscan, 256, 0, stream>>>(cnt, blocksum, n);
  scanB_kernel<<<1, 64, 0, stream>>>(blocksum, nscan);
  scanC_kernel<<<nscan, 256, 0, stream>>>(cnt, blocksum, row_start, dinv, n);
  fusedB_kernel<<<eb256 + sblocks, 256, 0, stream>>>(
      src, dst, lslot, blockhist, row_start, col, e, chunk, eb256, T, dinv, n);

  spmm_kernel<HID, true><<<spmm_blocks, 256, 0, stream>>>(T, row_start, cnt, col, dinv, b1, Hf, n);
  gemm_mfma_kernel<HID, HID><<<gemm_blocks, 256, 0, stream>>>(Hf, W2hi, W2lo, dinv, T, n);
  spmm_kernel<HID, true><<<spmm_blocks, 256, 0, stream>>>(T, row_start, cnt, col, dinv, b2, Hf, n);
  gemm_mfma_kernel<HID, DOUT><<<gemm_blocks, 256, 0, stream>>>(Hf, W3hi, W3lo, dinv, T, n);
  spmm_kernel<DOUT, false><<<spmm_blocks, 256, 0, stream>>>(T, row_start, cnt, col, dinv, b3, (float*)d_out, n);
}

// Round 12
// 422.386 us; speedup vs baseline: 1.1306x; 1.1306x over previous
//
#include <hip/hip_runtime.h>

// GCN 3-layer: N=50000, E=1.6M, D_IN=256, H=128, D_OUT=64, fp32 in/out.
// CSR build with ZERO global atomics: 256-block LDS histogram (16-bit packed
// counters, 2 slice passes), colscan -> per-(block,bin) exclusive offsets,
// atomic-free scatter fill. Per layer: split-bf16 MFMA GEMM -> CSR-SpMM.
// R11 lesson: keep big-LDS kernels standalone (fused blocks all inherit LDS).

constexpr int DIN = 256;
constexpr int HID = 128;
constexpr int DOUT = 64;
constexpr int NBLK = 256;     // histogram blocks (1 per CU)
constexpr int SLICE = 25600;  // bins per slice pass (packed 2/uint = 51200 B LDS)

typedef unsigned short ushort_t;
typedef unsigned int uint_t;
typedef __attribute__((ext_vector_type(8))) short bf16x8;
typedef __attribute__((ext_vector_type(4))) float f32x4;

__device__ inline ushort_t f2bf(float f) {
  uint_t u = __float_as_uint(f);
  u += 0x7FFF + ((u >> 16) & 1);  // RNE
  return (ushort_t)(u >> 16);
}
__device__ inline float bf2f(ushort_t b) {
  return __uint_as_float(((uint_t)b) << 16);
}

// ---------- weight prep: W[K][F] fp32 -> fragment bf16 hi/lo ----------
// Layout: Bp[t = n/16][s = k/32][lane = (k/8 % 4)*16 + n%16][j = k%8]

__device__ inline void wprep_one(const float* __restrict__ W, ushort_t* __restrict__ Bhi,
                                 ushort_t* __restrict__ Blo, int K, int F, int i) {
  int k = i / F, nn = i % F;
  int t = nn >> 4, s = k >> 5, q = (k >> 3) & 3, j = k & 7;
  int lane = q * 16 + (nn & 15);
  int KS = K >> 5;
  size_t idx = (((size_t)t * KS + s) * 64 + (size_t)lane) * 8 + j;
  float w = W[i];
  ushort_t h = f2bf(w);
  float r = w - bf2f(h);
  Bhi[idx] = h;
  Blo[idx] = f2bf(r);
}

__global__ __launch_bounds__(256) void wprep_kernel(
    const float* __restrict__ W1, ushort_t* __restrict__ W1hi, ushort_t* __restrict__ W1lo,
    const float* __restrict__ W2, ushort_t* __restrict__ W2hi, ushort_t* __restrict__ W2lo,
    const float* __restrict__ W3, ushort_t* __restrict__ W3hi, ushort_t* __restrict__ W3lo) {
  int idx = blockIdx.x * 256 + threadIdx.x;
  constexpr int S1 = DIN * HID;        // 32768
  constexpr int S2 = S1 + HID * HID;   // 49152
  constexpr int S3 = S2 + HID * DOUT;  // 57344
  if (idx < S1) wprep_one(W1, W1hi, W1lo, DIN, HID, idx);
  else if (idx < S2) wprep_one(W2, W2hi, W2lo, HID, HID, idx - S1);
  else if (idx < S3) wprep_one(W3, W3hi, W3lo, HID, DOUT, idx - S2);
}

// ---------- LDS histogram: 256 blocks, 2 slice passes, packed 16-bit bins ----------
// lslot[i] = within-(block,bin) arrival index; blockhist[b][bin] = count.

__global__ __launch_bounds__(512) void hist_kernel(const int* __restrict__ dst,
    ushort_t* __restrict__ blockhist, ushort_t* __restrict__ lslot,
    int e, int chunk, int n) {
  __shared__ uint_t h[SLICE / 2];
  int b = blockIdx.x;
  int i0 = b * chunk;
  int i1 = i0 + chunk; if (i1 > e) i1 = e;
#pragma unroll 1
  for (int s = 0; s < 2; ++s) {
    int base = s * SLICE;
    for (int j = threadIdx.x; j < SLICE / 2; j += 512) h[j] = 0;
    __syncthreads();
    for (int i = i0 + threadIdx.x; i < i1; i += 512) {
      int r = dst[i] - base;
      if (r >= 0 && r < SLICE) {
        int sh = (r & 1) * 16;
        uint_t old = atomicAdd(&h[r >> 1], 1u << sh);
        lslot[i] = (ushort_t)((old >> sh) & 0xFFFF);
      }
    }
    __syncthreads();
    for (int j = threadIdx.x; j < SLICE; j += 512) {
      int bin = base + j;
      if (bin < n) {
        int sh = (j & 1) * 16;
        blockhist[(size_t)b * n + bin] = (ushort_t)((h[j >> 1] >> sh) & 0xFFFF);
      }
    }
    __syncthreads();
  }
}

// ---------- colscan: per-bin exclusive scan over the 256 blocks; emit cnt ----------

__global__ __launch_bounds__(256) void colscan_kernel(ushort_t* __restrict__ blockhist,
    int* __restrict__ cnt, int n) {
  int d = blockIdx.x * 256 + threadIdx.x;
  if (d >= n) return;
  int run = 0;
#pragma unroll 4
  for (int b = 0; b < NBLK; ++b) {
    size_t idx = (size_t)b * n + d;
    int c = blockhist[idx];
    blockhist[idx] = (ushort_t)run;
    run += c;
  }
  cnt[d] = run;  // edges into d (deg-1)
}

// ---------- 3-phase exclusive scan of cnt, 1024 elems / block ----------

__global__ __launch_bounds__(256) void scanA_kernel(const int* __restrict__ cnt,
    int* __restrict__ blocksum, int n) {
  __shared__ int sums[256];
  int t = threadIdx.x;
  int base = blockIdx.x * 1024 + t * 4;
  int local = 0;
#pragma unroll
  for (int k = 0; k < 4; ++k) {
    int i = base + k;
    if (i < n) local += cnt[i];
  }
  sums[t] = local;
  __syncthreads();
  for (int off = 128; off > 0; off >>= 1) {
    if (t < off) sums[t] += sums[t + off];
    __syncthreads();
  }
  if (t == 0) blocksum[blockIdx.x] = sums[0];
}

__global__ __launch_bounds__(64) void scanB_kernel(int* __restrict__ blocksum, int nb) {
  int lane = threadIdx.x;
  int carry = 0;
  for (int base = 0; base < nb; base += 64) {
    int i = base + lane;
    int orig = (i < nb) ? blocksum[i] : 0;
    int v = orig;
#pragma unroll
    for (int off = 1; off < 64; off <<= 1) {
      int u = __shfl_up(v, off, 64);
      if (lane >= off) v += u;
    }
    int total = __shfl(v, 63, 64);
    if (i < nb) blocksum[i] = carry + v - orig;  // exclusive
    carry += total;
  }
}

__global__ __launch_bounds__(256) void scanC_kernel(const int* __restrict__ cnt,
    const int* __restrict__ blocksum, int* __restrict__ row_start,
    float* __restrict__ dinv, int n) {
  __shared__ int sums[256];
  int t = threadIdx.x;
  int base = blockIdx.x * 1024 + t * 4;
  int c[4];
  int local = 0;
#pragma unroll
  for (int k = 0; k < 4; ++k) {
    int i = base + k;
    c[k] = (i < n) ? cnt[i] : 0;
    local += c[k];
  }
  sums[t] = local;
  __syncthreads();
  for (int off = 1; off < 256; off <<= 1) {
    int v = (t >= off) ? sums[t - off] : 0;
    __syncthreads();
    sums[t] += v;
    __syncthreads();
  }
  int run = blocksum[blockIdx.x] + sums[t] - local;  // exclusive offset
#pragma unroll
  for (int k = 0; k < 4; ++k) {
    int i = base + k;
    if (i < n) {
      row_start[i] = run;
      dinv[i] = rsqrtf((float)(c[k] + 1));
      run += c[k];
    }
  }
}

// ---------- fill: atomic-free scatter ----------

__global__ void fill_kernel(const int* __restrict__ src, const int* __restrict__ dst,
    const ushort_t* __restrict__ lslot, const ushort_t* __restrict__ blockhist,
    const int* __restrict__ row_start, int* __restrict__ col,
    int e, int chunk, int n) {
  int i = blockIdx.x * blockDim.x + threadIdx.x;
  if (i >= e) return;
  int d = dst[i];
  int b = i / chunk;
  int pos = row_start[d] + (int)blockhist[(size_t)b * n + d] + (int)lslot[i];
  col[pos] = src[i];
}

// ---------- split-bf16 MFMA GEMM ----------
// 256 threads = 4 waves; 64 rows/block; wave w: rows +16w..+16w+15.
// acc = Ahi*Bhi + Alo*Bhi + Ahi*Blo (fp32 accum; lo*lo dropped, ~2^-18 rel).

template <int K, int F>
__global__ __launch_bounds__(256) void gemm_mfma_kernel(const float* __restrict__ X,
    const ushort_t* __restrict__ Bhi, const ushort_t* __restrict__ Blo,
    const float* __restrict__ dinv, ushort_t* __restrict__ T, int n) {
  constexpr int NT = F / 16;   // n-tiles
  constexpr int KS = K / 32;   // k-steps
  int bid = blockIdx.x;
  int wave = threadIdx.x >> 6;
  int lane = threadIdx.x & 63;
  int q = lane >> 4;
  int m = lane & 15;
  int arow = bid * 64 + wave * 16 + m;
  bool valid = arow < n;
  const float* xrow = X + (size_t)arow * K;

  f32x4 acc[NT];
#pragma unroll
  for (int t = 0; t < NT; ++t) acc[t] = (f32x4){0.f, 0.f, 0.f, 0.f};

  for (int s = 0; s < KS; ++s) {
    float av[8];
    if (valid) {
      float4 u0 = *(const float4*)(xrow + s * 32 + q * 8);
      float4 u1 = *(const float4*)(xrow + s * 32 + q * 8 + 4);
      av[0] = u0.x; av[1] = u0.y; av[2] = u0.z; av[3] = u0.w;
      av[4] = u1.x; av[5] = u1.y; av[6] = u1.z; av[7] = u1.w;
    } else {
#pragma unroll
      for (int j = 0; j < 8; ++j) av[j] = 0.f;
    }
    bf16x8 ahi, alo;
#pragma unroll
    for (int j = 0; j < 8; ++j) {
      ushort_t h = f2bf(av[j]);
      ahi[j] = (short)h;
      alo[j] = (short)f2bf(av[j] - bf2f(h));
    }
#pragma unroll
    for (int t = 0; t < NT; ++t) {
      size_t boff = (((size_t)t * KS + s) * 64 + (size_t)lane) * 8;
      bf16x8 bh = *(const bf16x8*)(Bhi + boff);
      bf16x8 bl = *(const bf16x8*)(Blo + boff);
      acc[t] = __builtin_amdgcn_mfma_f32_16x16x32_bf16(ahi, bh, acc[t], 0, 0, 0);
      acc[t] = __builtin_amdgcn_mfma_f32_16x16x32_bf16(alo, bh, acc[t], 0, 0, 0);
      acc[t] = __builtin_amdgcn_mfma_f32_16x16x32_bf16(ahi, bl, acc[t], 0, 0, 0);
    }
  }

  int orow_base = bid * 64 + wave * 16 + q * 4;
#pragma unroll
  for (int r = 0; r < 4; ++r) {
    int orow = orow_base + r;
    if (orow >= n) continue;
    float sc = dinv[orow];
    ushort_t* trow = T + (size_t)orow * F + m;
#pragma unroll
    for (int t = 0; t < NT; ++t) trow[t * 16] = f2bf(sc * acc[t][r]);
  }
}

// ---------- CSR SpMM: out[d] = dinv[d]*(t'[d] + sum_c t'[c]) + b, opt ReLU ----------
// t' rows bf16, pre-scaled by dinv[row]. TWO destination nodes per wave.

template <int F, bool RELU>
__global__ __launch_bounds__(256) void spmm_kernel(const ushort_t* __restrict__ t,
    const int* __restrict__ row_start, const int* __restrict__ cntArr,
    const int* __restrict__ col, const float* __restrict__ dinv,
    const float* __restrict__ bias, float* __restrict__ out, int n) {
  int gw = (int)((blockIdx.x * 256u + threadIdx.x) >> 6);
  int lane = threadIdx.x & 63;
  int n0 = gw * 2;
  int n1 = n0 + 1;
  if (n0 >= n) return;
  bool h1 = (n1 < n);
  int rs0 = __builtin_amdgcn_readfirstlane(row_start[n0]);
  int e0 = __builtin_amdgcn_readfirstlane(cntArr[n0]);
  int rs1 = h1 ? __builtin_amdgcn_readfirstlane(row_start[n1]) : 0;
  int e1 = h1 ? __builtin_amdgcn_readfirstlane(cntArr[n1]) : 0;
  float di0 = dinv[n0];
  float di1 = h1 ? dinv[n1] : 0.f;

  if constexpr (F == 128) {
    uint_t s0 = ((const uint_t*)(t + (size_t)n0 * F))[lane];
    float ax0 = bf2f((ushort_t)(s0 & 0xFFFF)), ay0 = bf2f((ushort_t)(s0 >> 16));
    float ax1 = 0.f, ay1 = 0.f;
    if (h1) {
      uint_t s1 = ((const uint_t*)(t + (size_t)n1 * F))[lane];
      ax1 = bf2f((ushort_t)(s1 & 0xFFFF)); ay1 = bf2f((ushort_t)(s1 >> 16));
    }
    int p0 = rs0, q0 = rs0 + e0;
    int p1 = rs1, q1 = rs1 + e1;
    while (p0 + 4 <= q0 && p1 + 4 <= q1) {
      int c[8];
      uint_t v[8];
#pragma unroll
      for (int j = 0; j < 4; ++j) { c[j] = col[p0 + j]; c[4 + j] = col[p1 + j]; }
#pragma unroll
      for (int j = 0; j < 8; ++j) v[j] = ((const uint_t*)(t + (size_t)c[j] * F))[lane];
#pragma unroll
      for (int j = 0; j < 4; ++j) {
        ax0 += bf2f((ushort_t)(v[j] & 0xFFFF));
        ay0 += bf2f((ushort_t)(v[j] >> 16));
        ax1 += bf2f((ushort_t)(v[4 + j] & 0xFFFF));
        ay1 += bf2f((ushort_t)(v[4 + j] >> 16));
      }
      p0 += 4; p1 += 4;
    }
    for (; p0 + 4 <= q0; p0 += 4) {
      int c[4]; uint_t v[4];
#pragma unroll
      for (int j = 0; j < 4; ++j) c[j] = col[p0 + j];
#pragma unroll
      for (int j = 0; j < 4; ++j) v[j] = ((const uint_t*)(t + (size_t)c[j] * F))[lane];
#pragma unroll
      for (int j = 0; j < 4; ++j) {
        ax0 += bf2f((ushort_t)(v[j] & 0xFFFF)); ay0 += bf2f((ushort_t)(v[j] >> 16));
      }
    }
    for (; p0 < q0; ++p0) {
      uint_t v = ((const uint_t*)(t + (size_t)col[p0] * F))[lane];
      ax0 += bf2f((ushort_t)(v & 0xFFFF)); ay0 += bf2f((ushort_t)(v >> 16));
    }
    for (; p1 + 4 <= q1; p1 += 4) {
      int c[4]; uint_t v[4];
#pragma unroll
      for (int j = 0; j < 4; ++j) c[j] = col[p1 + j];
#pragma unroll
      for (int j = 0; j < 4; ++j) v[j] = ((const uint_t*)(t + (size_t)c[j] * F))[lane];
#pragma unroll
      for (int j = 0; j < 4; ++j) {
        ax1 += bf2f((ushort_t)(v[j] & 0xFFFF)); ay1 += bf2f((ushort_t)(v[j] >> 16));
      }
    }
    for (; p1 < q1; ++p1) {
      uint_t v = ((const uint_t*)(t + (size_t)col[p1] * F))[lane];
      ax1 += bf2f((ushort_t)(v & 0xFFFF)); ay1 += bf2f((ushort_t)(v >> 16));
    }
    float bx = bias[2 * lane], by = bias[2 * lane + 1];
    ax0 = fmaf(di0, ax0, bx); ay0 = fmaf(di0, ay0, by);
    if constexpr (RELU) { ax0 = fmaxf(ax0, 0.f); ay0 = fmaxf(ay0, 0.f); }
    float2 o0; o0.x = ax0; o0.y = ay0;
    ((float2*)(out + (size_t)n0 * F))[lane] = o0;
    if (h1) {
      ax1 = fmaf(di1, ax1, bx); ay1 = fmaf(di1, ay1, by);
      if constexpr (RELU) { ax1 = fmaxf(ax1, 0.f); ay1 = fmaxf(ay1, 0.f); }
      float2 o1; o1.x = ax1; o1.y = ay1;
      ((float2*)(out + (size_t)n1 * F))[lane] = o1;
    }
  } else {  // F == 64: one bf16 per lane
    float a0 = bf2f(t[(size_t)n0 * F + lane]);
    float a1 = h1 ? bf2f(t[(size_t)n1 * F + lane]) : 0.f;
    int p0 = rs0, q0 = rs0 + e0;
    int p1 = rs1, q1 = rs1 + e1;
    while (p0 + 4 <= q0 && p1 + 4 <= q1) {
      int c[8];
      ushort_t v[8];
#pragma unroll
      for (int j = 0; j < 4; ++j) { c[j] = col[p0 + j]; c[4 + j] = col[p1 + j]; }
#pragma unroll
      for (int j = 0; j < 8; ++j) v[j] = t[(size_t)c[j] * F + lane];
#pragma unroll
      for (int j = 0; j < 4; ++j) { a0 += bf2f(v[j]); a1 += bf2f(v[4 + j]); }
      p0 += 4; p1 += 4;
    }
    for (; p0 + 4 <= q0; p0 += 4) {
      int c[4]; ushort_t v[4];
#pragma unroll
      for (int j = 0; j < 4; ++j) c[j] = col[p0 + j];
#pragma unroll
      for (int j = 0; j < 4; ++j) v[j] = t[(size_t)c[j] * F + lane];
#pragma unroll
      for (int j = 0; j < 4; ++j) a0 += bf2f(v[j]);
    }
    for (; p0 < q0; ++p0) a0 += bf2f(t[(size_t)col[p0] * F + lane]);
    for (; p1 + 4 <= q1; p1 += 4) {
      int c[4]; ushort_t v[4];
#pragma unroll
      for (int j = 0; j < 4; ++j) c[j] = col[p1 + j];
#pragma unroll
      for (int j = 0; j < 4; ++j) v[j] = t[(size_t)c[j] * F + lane];
#pragma unroll
      for (int j = 0; j < 4; ++j) a1 += bf2f(v[j]);
    }
    for (; p1 < q1; ++p1) a1 += bf2f(t[(size_t)col[p1] * F + lane]);
    float b = bias[lane];
    a0 = fmaf(di0, a0, b);
    if constexpr (RELU) a0 = fmaxf(a0, 0.f);
    out[(size_t)n0 * F + lane] = a0;
    if (h1) {
      a1 = fmaf(di1, a1, b);
      if constexpr (RELU) a1 = fmaxf(a1, 0.f);
      out[(size_t)n1 * F + lane] = a1;
    }
  }
}

// ---------- launch ----------

extern "C" void kernel_launch(void* const* d_in, const int* in_sizes, int n_in,
                              void* d_out, int out_size, void* d_ws, size_t ws_size,
                              hipStream_t stream) {
  const float* x  = (const float*)d_in[0];
  const float* W1 = (const float*)d_in[1];
  const float* b1 = (const float*)d_in[2];
  const float* W2 = (const float*)d_in[3];
  const float* b2 = (const float*)d_in[4];
  const float* W3 = (const float*)d_in[5];
  const float* b3 = (const float*)d_in[6];
  const int* ei   = (const int*)d_in[7];  // harness delivers integers as int32

  int n = in_sizes[0] / DIN;
  int e = in_sizes[7] / 2;
  const int* src = ei;
  const int* dst = ei + e;
  int chunk = (e + NBLK - 1) / NBLK;

  char* ws = (char*)d_ws;
  size_t off = 0;
  auto alloc = [&](size_t bytes) -> void* {
    off = (off + 255) & ~(size_t)255;
    void* p = ws + off;
    off += bytes;
    return p;
  };
  int nscan = (n + 1023) / 1024;
  ushort_t* blockhist = (ushort_t*)alloc((size_t)NBLK * n * 2);  // 25.6 MB
  ushort_t* lslot     = (ushort_t*)alloc((size_t)e * 2);
  int*      cnt       = (int*)alloc((size_t)n * 4);
  float*    dinv      = (float*)alloc((size_t)n * 4);
  int*      row_start = (int*)alloc((size_t)n * 4);
  int*      blocksum  = (int*)alloc((size_t)nscan * 4);
  int*      col       = (int*)alloc((size_t)e * 4);
  ushort_t* T         = (ushort_t*)alloc((size_t)n * HID * 2);  // bf16 GEMM out
  float*    Hf        = (float*)alloc((size_t)n * HID * 4);     // fp32 SpMM out
  ushort_t* W1hi      = (ushort_t*)alloc((size_t)DIN * HID * 2);
  ushort_t* W1lo      = (ushort_t*)alloc((size_t)DIN * HID * 2);
  ushort_t* W2hi      = (ushort_t*)alloc((size_t)HID * HID * 2);
  ushort_t* W2lo      = (ushort_t*)alloc((size_t)HID * HID * 2);
  ushort_t* W3hi      = (ushort_t*)alloc((size_t)HID * DOUT * 2);
  ushort_t* W3lo      = (ushort_t*)alloc((size_t)HID * DOUT * 2);
  (void)ws_size;

  int eb256 = (e + 255) / 256;
  int gemm_blocks = (n + 63) / 64;
  int nwaves = (n + 1) / 2;                 // 2 nodes per wave
  int spmm_blocks = (nwaves + 3) / 4;       // 4 waves per block
  constexpr int WPREP_TOTAL = DIN * HID + HID * HID + HID * DOUT;  // 57344
  int wblocks = (WPREP_TOTAL + 255) / 256;  // 224

  wprep_kernel<<<wblocks, 256, 0, stream>>>(
      W1, W1hi, W1lo, W2, W2hi, W2lo, W3, W3hi, W3lo);
  hist_kernel<<<NBLK, 512, 0, stream>>>(dst, blockhist, lslot, e, chunk, n);
  colscan_kernel<<<(n + 255) / 256, 256, 0, stream>>>(blockhist, cnt, n);
  scanA_kernel<<<nscan, 256, 0, stream>>>(cnt, blocksum, n);
  scanB_kernel<<<1, 64, 0, stream>>>(blocksum, nscan);
  scanC_kernel<<<nscan, 256, 0, stream>>>(cnt, blocksum, row_start, dinv, n);
  gemm_mfma_kernel<DIN, HID><<<gemm_blocks, 256, 0, stream>>>(x, W1hi, W1lo, dinv, T, n);
  fill_kernel<<<eb256, 256, 0, stream>>>(src, dst, lslot, blockhist, row_start, col, e, chunk, n);

  spmm_kernel<HID, true><<<spmm_blocks, 256, 0, stream>>>(T, row_start, cnt, col, dinv, b1, Hf, n);
  gemm_mfma_kernel<HID, HID><<<gemm_blocks, 256, 0, stream>>>(Hf, W2hi, W2lo, dinv, T, n);
  spmm_kernel<HID, true><<<spmm_blocks, 256, 0, stream>>>(T, row_start, cnt, col, dinv, b2, Hf, n);
  gemm_mfma_kernel<HID, DOUT><<<gemm_blocks, 256, 0, stream>>>(Hf, W3hi, W3lo, dinv, T, n);
  spmm_kernel<DOUT, false><<<spmm_blocks, 256, 0, stream>>>(T, row_start, cnt, col, dinv, b3, (float*)d_out, n);
}